// Round 1
// baseline (5298.541 us; speedup 1.0000x reference)
//
#include <hip/hip_runtime.h>
#include <cmath>

// Problem constants
#define NNODES 60000
#define D      200

constexpr int RT  = 32;        // rows per block (60000 % 32 == 0 -> 1875 blocks, no tail)
constexpr int BK  = 16;        // K-tile
constexpr int NT  = 256;       // padded output-column tile (covers N=200/250)
constexpr int RTP = RT + 4;    // aT pitch (pad)
constexpr int BUFP = 208;      // LDS row buffer pitch

__device__ __forceinline__ float sgm(float x) { return 1.0f / (1.0f + expf(-x)); }

// Stage one BK x RT A-tile (transposed) and BK x NT W-tile into LDS.
// A: segment1 = global strided / gathered / LDS;  segment2 = global strided / LDS.
// W: element (col,k) = k < KW1 ? wa[col*wap + k] : wb[col*wbp + (k-KW1)]
__device__ __forceinline__ void stage_tile(
    float (*aT)[RTP], float (*wt)[NT], int row0, int k0,
    const float* a1g, int a1pitch, const int* gidx, const float* a1l, int a1lp, int K1,
    const float* a2g, int a2pitch, const float* a2l, int a2lp, int K2,
    const float* wa, int wap, int KW1, const float* wb, int wbp,
    int ncols, int tid)
{
    const int Ktot = K1 + K2;
    // ---- A tile: 2 elements per thread ----
    {
        const int kk = tid & 15;
        const int k  = k0 + kk;
        #pragma unroll
        for (int h = 0; h < 2; ++h) {
            const int r = (tid >> 4) + h * 16;
            float v = 0.0f;
            if (k < K1) {
                if (a1l) {
                    v = a1l[r * a1lp + k];
                } else {
                    const long rb = gidx ? (long)gidx[row0 + r] * a1pitch
                                         : (long)(row0 + r) * a1pitch;
                    v = a1g[rb + k];
                }
            } else if (k < Ktot) {
                if (a2l) v = a2l[r * a2lp + (k - K1)];
                else     v = a2g[(long)(row0 + r) * a2pitch + (k - K1)];
            }
            aT[kk][r] = v;
        }
    }
    // ---- W tile: 16 elements per thread (one column) ----
    {
        const int col = tid;
        #pragma unroll
        for (int kk = 0; kk < BK; ++kk) {
            const int k = k0 + kk;
            float v = 0.0f;
            if (col < ncols && k < Ktot) {
                if (k < KW1) v = wa[(long)col * wap + k];
                else         v = wb[(long)col * wbp + (k - KW1)];
            }
            wt[kk][col] = v;
        }
    }
}

__device__ __forceinline__ void mm_inner(const float (*aT)[RTP], const float (*wt)[NT],
                                         float acc[8][4], int tr, int tc)
{
    #pragma unroll
    for (int kk = 0; kk < BK; ++kk) {
        const float w0 = wt[kk][tc * 4 + 0];
        const float w1 = wt[kk][tc * 4 + 1];
        const float w2 = wt[kk][tc * 4 + 2];
        const float w3 = wt[kk][tc * 4 + 3];
        #pragma unroll
        for (int j = 0; j < 8; ++j) {
            const float a = aT[kk][tr * 8 + j];
            acc[j][0] = fmaf(a, w0, acc[j][0]);
            acc[j][1] = fmaf(a, w1, acc[j][1]);
            acc[j][2] = fmaf(a, w2, acc[j][2]);
            acc[j][3] = fmaf(a, w3, acc[j][3]);
        }
    }
}

__device__ __forceinline__ void run_gemm(
    float (*aT)[RTP], float (*wt)[NT], float acc[8][4], int row0,
    const float* a1g, int a1pitch, const int* gidx, const float* a1l, int a1lp, int K1,
    const float* a2g, int a2pitch, const float* a2l, int a2lp, int K2,
    const float* wa, int wap, int KW1, const float* wb, int wbp,
    int ncols, int tid, int tr, int tc)
{
    #pragma unroll
    for (int j = 0; j < 8; ++j)
        #pragma unroll
        for (int i = 0; i < 4; ++i) acc[j][i] = 0.0f;
    const int Ktot = K1 + K2;
    for (int k0 = 0; k0 < Ktot; k0 += BK) {
        __syncthreads();   // protect previous tile reads / prior LDS writes
        stage_tile(aT, wt, row0, k0,
                   a1g, a1pitch, gidx, a1l, a1lp, K1,
                   a2g, a2pitch, a2l, a2lp, K2,
                   wa, wap, KW1, wb, wbp, ncols, tid);
        __syncthreads();
        mm_inner(aT, wt, acc, tr, tc);
    }
}

__global__ __launch_bounds__(256)
void fused_kernel(const int* __restrict__ tok,
                  const float* __restrict__ chc,
                  const float* __restrict__ chh,
                  const float* __restrict__ emb,
                  const float* __restrict__ p1w,  const float* __restrict__ p1b,
                  const float* __restrict__ p2w,  const float* __restrict__ p2b,
                  const float* __restrict__ ixw,  const float* __restrict__ ixb,
                  const float* __restrict__ ihw,  const float* __restrict__ ihb,
                  const float* __restrict__ fxw,  const float* __restrict__ fxb,
                  const float* __restrict__ fhw,  const float* __restrict__ fhb,
                  const float* __restrict__ uxw,  const float* __restrict__ uxb,
                  const float* __restrict__ uhw,  const float* __restrict__ uhb,
                  const float* __restrict__ oxw,  const float* __restrict__ oxb,
                  const float* __restrict__ ohw,  const float* __restrict__ ohb,
                  const float* __restrict__ fc2w, const float* __restrict__ fc2b,
                  float* __restrict__ out)
{
    __shared__ float aT[BK][RTP];
    __shared__ float wt[BK][NT];
    __shared__ float buf[RT][BUFP];   // holds: control -> hs -> h

    const int tid = threadIdx.x;
    const int tr  = tid >> 6;     // 0..3  (wave id); rows tr*8 .. tr*8+7
    const int tc  = tid & 63;     // 0..63; cols tc*4 .. tc*4+3
    const int c0  = tc * 4;
    const int row0 = blockIdx.x * RT;

    float acc[8][4];

    // ---- control = relu([ch0|ch1|ch2] @ p1_w^T + p1_b) -> buf ----
    run_gemm(aT, wt, acc, row0,
             chh, 800, nullptr, nullptr, 0, 600,
             nullptr, 0, nullptr, 0, 0,
             p1w, 600, 600, nullptr, 0,
             D, tid, tr, tc);
    if (c0 < D) {
        const float4 b = *reinterpret_cast<const float4*>(&p1b[c0]);
        #pragma unroll
        for (int j = 0; j < 8; ++j) {
            const int r = tr * 8 + j;
            buf[r][c0 + 0] = fmaxf(acc[j][0] + b.x, 0.0f);
            buf[r][c0 + 1] = fmaxf(acc[j][1] + b.y, 0.0f);
            buf[r][c0 + 2] = fmaxf(acc[j][2] + b.z, 0.0f);
            buf[r][c0 + 3] = fmaxf(acc[j][3] + b.w, 0.0f);
        }
    }
    // (run_gemm's first __syncthreads protects buf before the next staging reads it)

    // ---- hs = relu([control | ch3] @ p2_w^T + p2_b) -> buf (overwrite) ----
    run_gemm(aT, wt, acc, row0,
             nullptr, 0, nullptr, &buf[0][0], BUFP, 200,
             chh + 600, 800, nullptr, 0, 200,
             p2w, 400, 400, nullptr, 0,
             D, tid, tr, tc);
    if (c0 < D) {
        const float4 b = *reinterpret_cast<const float4*>(&p2b[c0]);
        #pragma unroll
        for (int j = 0; j < 8; ++j) {
            const int r = tr * 8 + j;
            buf[r][c0 + 0] = fmaxf(acc[j][0] + b.x, 0.0f);
            buf[r][c0 + 1] = fmaxf(acc[j][1] + b.y, 0.0f);
            buf[r][c0 + 2] = fmaxf(acc[j][2] + b.z, 0.0f);
            buf[r][c0 + 3] = fmaxf(acc[j][3] + b.w, 0.0f);
        }
    }

    // ---- fx = x @ fx_w^T + fx_b (x = emb[tok]) ----
    run_gemm(aT, wt, acc, row0,
             emb, D, tok, nullptr, 0, 200,
             nullptr, 0, nullptr, 0, 0,
             fxw, 200, 200, nullptr, 0,
             D, tid, tr, tc);
    float fxr[8][4];
    {
        float4 b = make_float4(0.f, 0.f, 0.f, 0.f);
        if (c0 < D) b = *reinterpret_cast<const float4*>(&fxb[c0]);
        #pragma unroll
        for (int j = 0; j < 8; ++j) {
            fxr[j][0] = acc[j][0] + b.x;
            fxr[j][1] = acc[j][1] + b.y;
            fxr[j][2] = acc[j][2] + b.z;
            fxr[j][3] = acc[j][3] + b.w;
        }
    }

    // ---- csum = sum_c sigmoid(ch_c @ fh_w^T + fh_b + fx) * child_c ----
    float csum[8][4];
    #pragma unroll
    for (int j = 0; j < 8; ++j)
        #pragma unroll
        for (int i = 0; i < 4; ++i) csum[j][i] = 0.0f;
    for (int cc_ = 0; cc_ < 4; ++cc_) {
        run_gemm(aT, wt, acc, row0,
                 chh + cc_ * 200, 800, nullptr, nullptr, 0, 200,
                 nullptr, 0, nullptr, 0, 0,
                 fhw, 200, 200, nullptr, 0,
                 D, tid, tr, tc);
        if (c0 < D) {
            const float4 b = *reinterpret_cast<const float4*>(&fhb[c0]);
            #pragma unroll
            for (int j = 0; j < 8; ++j) {
                const long r = row0 + tr * 8 + j;
                const float4 cv = *reinterpret_cast<const float4*>(&chc[r * 800 + cc_ * 200 + c0]);
                csum[j][0] += sgm(acc[j][0] + b.x + fxr[j][0]) * cv.x;
                csum[j][1] += sgm(acc[j][1] + b.y + fxr[j][1]) * cv.y;
                csum[j][2] += sgm(acc[j][2] + b.z + fxr[j][2]) * cv.z;
                csum[j][3] += sgm(acc[j][3] + b.w + fxr[j][3]) * cv.w;
            }
        }
    }

    // ---- i = sigmoid(x@ix^T + ix_b + hs@ih^T + ih_b) ----
    run_gemm(aT, wt, acc, row0,
             emb, D, tok, nullptr, 0, 200,
             nullptr, 0, &buf[0][0], BUFP, 200,
             ixw, 200, 200, ihw, 200,
             D, tid, tr, tc);
    float gi[8][4];
    {
        float4 b1 = make_float4(0.f,0.f,0.f,0.f), b2 = b1;
        if (c0 < D) { b1 = *reinterpret_cast<const float4*>(&ixb[c0]);
                      b2 = *reinterpret_cast<const float4*>(&ihb[c0]); }
        #pragma unroll
        for (int j = 0; j < 8; ++j) {
            gi[j][0] = sgm(acc[j][0] + b1.x + b2.x);
            gi[j][1] = sgm(acc[j][1] + b1.y + b2.y);
            gi[j][2] = sgm(acc[j][2] + b1.z + b2.z);
            gi[j][3] = sgm(acc[j][3] + b1.w + b2.w);
        }
    }

    // ---- u = tanh(x@ux^T + ux_b + hs@uh^T + uh_b);  cval = i*u + csum ----
    run_gemm(aT, wt, acc, row0,
             emb, D, tok, nullptr, 0, 200,
             nullptr, 0, &buf[0][0], BUFP, 200,
             uxw, 200, 200, uhw, 200,
             D, tid, tr, tc);
    float cval[8][4];
    {
        float4 b1 = make_float4(0.f,0.f,0.f,0.f), b2 = b1;
        if (c0 < D) { b1 = *reinterpret_cast<const float4*>(&uxb[c0]);
                      b2 = *reinterpret_cast<const float4*>(&uhb[c0]); }
        #pragma unroll
        for (int j = 0; j < 8; ++j) {
            cval[j][0] = gi[j][0] * tanhf(acc[j][0] + b1.x + b2.x) + csum[j][0];
            cval[j][1] = gi[j][1] * tanhf(acc[j][1] + b1.y + b2.y) + csum[j][1];
            cval[j][2] = gi[j][2] * tanhf(acc[j][2] + b1.z + b2.z) + csum[j][2];
            cval[j][3] = gi[j][3] * tanhf(acc[j][3] + b1.w + b2.w) + csum[j][3];
        }
    }

    // ---- o gate; h = sigmoid(o)*tanh(c) -> buf ----
    run_gemm(aT, wt, acc, row0,
             emb, D, tok, nullptr, 0, 200,
             nullptr, 0, &buf[0][0], BUFP, 200,
             oxw, 200, 200, ohw, 200,
             D, tid, tr, tc);
    if (c0 < D) {
        const float4 b1 = *reinterpret_cast<const float4*>(&oxb[c0]);
        const float4 b2 = *reinterpret_cast<const float4*>(&ohb[c0]);
        #pragma unroll
        for (int j = 0; j < 8; ++j) {
            const int r = tr * 8 + j;
            buf[r][c0 + 0] = sgm(acc[j][0] + b1.x + b2.x) * tanhf(cval[j][0]);
            buf[r][c0 + 1] = sgm(acc[j][1] + b1.y + b2.y) * tanhf(cval[j][1]);
            buf[r][c0 + 2] = sgm(acc[j][2] + b1.z + b2.z) * tanhf(cval[j][2]);
            buf[r][c0 + 3] = sgm(acc[j][3] + b1.w + b2.w) * tanhf(cval[j][3]);
        }
    }

    // ---- logits = h @ fc2_w^T + fc2_b -> out ----
    run_gemm(aT, wt, acc, row0,
             nullptr, 0, nullptr, &buf[0][0], BUFP, 200,
             nullptr, 0, nullptr, 0, 0,
             fc2w, 200, 200, nullptr, 0,
             250, tid, tr, tc);
    #pragma unroll
    for (int j = 0; j < 8; ++j) {
        const long r = row0 + tr * 8 + j;
        #pragma unroll
        for (int i = 0; i < 4; ++i) {
            const int col = c0 + i;
            if (col < 250) out[r * 250 + col] = acc[j][i] + fc2b[col];
        }
    }
}

extern "C" void kernel_launch(void* const* d_in, const int* in_sizes, int n_in,
                              void* d_out, int out_size, void* d_ws, size_t ws_size,
                              hipStream_t stream)
{
    const int*   tok  = (const int*)  d_in[0];
    const float* chc  = (const float*)d_in[1];
    const float* chh  = (const float*)d_in[2];
    const float* emb  = (const float*)d_in[3];
    const float* p1w  = (const float*)d_in[4];
    const float* p1b  = (const float*)d_in[5];
    const float* p2w  = (const float*)d_in[6];
    const float* p2b  = (const float*)d_in[7];
    const float* ixw  = (const float*)d_in[8];
    const float* ixb  = (const float*)d_in[9];
    const float* ihw  = (const float*)d_in[10];
    const float* ihb  = (const float*)d_in[11];
    const float* fxw  = (const float*)d_in[12];
    const float* fxb  = (const float*)d_in[13];
    const float* fhw  = (const float*)d_in[14];
    const float* fhb  = (const float*)d_in[15];
    const float* uxw  = (const float*)d_in[16];
    const float* uxb  = (const float*)d_in[17];
    const float* uhw  = (const float*)d_in[18];
    const float* uhb  = (const float*)d_in[19];
    const float* oxw  = (const float*)d_in[20];
    const float* oxb  = (const float*)d_in[21];
    const float* ohw  = (const float*)d_in[22];
    const float* ohb  = (const float*)d_in[23];
    const float* fc2w = (const float*)d_in[24];
    const float* fc2b = (const float*)d_in[25];
    float* out = (float*)d_out;

    dim3 grid(NNODES / RT);   // 1875 blocks, exact (no row tail)
    hipLaunchKernelGGL(fused_kernel, grid, dim3(256), 0, stream,
                       tok, chc, chh, emb,
                       p1w, p1b, p2w, p2b,
                       ixw, ixb, ihw, ihb,
                       fxw, fxb, fhw, fhb,
                       uxw, uxb, uhw, uhb,
                       oxw, oxb, ohw, ohb,
                       fc2w, fc2b, out);
}

// Round 3
// 363.825 us; speedup vs baseline: 14.5634x; 14.5634x over previous
//
#include <hip/hip_runtime.h>
#include <cmath>

#define NNODES 60000
#define DDIM   200
#define NCLS   250

constexpr int R   = 64;    // rows per block
constexpr int BK  = 32;    // K-tile (one MFMA K-step)
constexpr int XP  = 232;   // pitch (bf16 elems) for pitched LDS bufs (2-way bank max)

typedef float  f32x4  __attribute__((ext_vector_type(4)));
typedef short  short8 __attribute__((ext_vector_type(8)));

// ---- ws layout (bf16 elems). All mats [256][Kpad], rows>=ncols zero, k>=Kreal zero.
constexpr int W_P1  = 0;              // [256][608]
constexpr int W_P2A = 155648;         // [256][224] each below
constexpr int W_P2B = 212992;
constexpr int W_FX  = 270336;
constexpr int W_FH  = 327680;
constexpr int W_IX  = 385024;
constexpr int W_IH  = 442368;
constexpr int W_UX  = 499712;
constexpr int W_UH  = 557056;
constexpr int W_OX  = 614400;
constexpr int W_OH  = 671744;
constexpr int W_FC2 = 729088;
constexpr int W_TOTAL_ELEMS = 786432;                 // *2 = 1,572,864 bytes
constexpr size_t W_TOTAL_BYTES = (size_t)W_TOTAL_ELEMS * 2;

__device__ __forceinline__ short f2b(float f) {
    union { float f; unsigned u; } x; x.f = f;
    unsigned r = (x.u + 0x7FFFu + ((x.u >> 16) & 1u)) >> 16;   // RNE
    return (short)r;
}
__device__ __forceinline__ float b2f(short s) {
    union { unsigned u; float f; } x; x.u = ((unsigned)(unsigned short)s) << 16;
    return x.f;
}
__device__ __forceinline__ float sgm(float x)  { return 1.0f / (1.0f + __expf(-x)); }
__device__ __forceinline__ float tanh_fast(float x) { return 1.0f - 2.0f / (__expf(2.0f * x) + 1.0f); }
__device__ __forceinline__ int   swz(int b)    { return b ^ (((b >> 7) & 3) << 4); }

// ================= weight prepass: fp32 -> bf16 padded mats in ws =================
__global__ void wprep(const float* __restrict__ p1w, const float* __restrict__ p2w,
                      const float* __restrict__ fxw, const float* __restrict__ fhw,
                      const float* __restrict__ ixw, const float* __restrict__ ihw,
                      const float* __restrict__ uxw, const float* __restrict__ uhw,
                      const float* __restrict__ oxw, const float* __restrict__ ohw,
                      const float* __restrict__ fc2w, short* __restrict__ ws)
{
    int i = blockIdx.x * 256 + threadIdx.x;
    if (i >= W_TOTAL_ELEMS) return;
    float v = 0.0f;
    if (i < W_P2A) {                       // p1: [256][608], src 200x600
        int n = i / 608, k = i % 608;
        if (n < 200 && k < 600) v = p1w[n * 600 + k];
        ws[i] = f2b(v); return;
    }
    int j = i - W_P2A;
    int m = j / 57344, rem = j % 57344;
    int n = rem / 224, k = rem % 224;
    const float* src; int stride = 200, off = 0, ncols = 200;
    switch (m) {
        case 0:  src = p2w; stride = 400; break;
        case 1:  src = p2w; stride = 400; off = 200; break;
        case 2:  src = fxw; break;
        case 3:  src = fhw; break;
        case 4:  src = ixw; break;
        case 5:  src = ihw; break;
        case 6:  src = uxw; break;
        case 7:  src = uhw; break;
        case 8:  src = oxw; break;
        case 9:  src = ohw; break;
        default: src = fc2w; ncols = 250; break;
    }
    if (n < ncols && k < 200) v = src[n * stride + off + k];
    ws[i] = f2b(v);
}

// ================= fused MFMA kernel =================
__device__ __forceinline__ void gload16(const void* g, void* l) {
    __builtin_amdgcn_global_load_lds((const __attribute__((address_space(1))) unsigned*)g,
                                     (__attribute__((address_space(3))) unsigned*)l, 16, 0, 0);
}

__device__ __forceinline__ void stage_w(const short* __restrict__ wmat, int Kpad, int t,
                                        int wrows, int wv, short* w_sw)
{
    const int issues = wrows >> 4;               // 1KB per issue (64 lanes x 16B)
    for (int q = wv; q < issues; q += 4) {
        // per-lane source computed from LINEAR dest unit; swizzle folded into source addr
        const int lane = threadIdx.x & 63;
        const int db = q * 1024 + lane * 16;     // linear dest byte of this lane
        const int n  = db >> 6;                  // LDS row (64B rows)
        const int g  = (db >> 4) & 3;
        const int gs = g ^ ((n >> 1) & 3);       // inverse swizzle on source
        const short* src = wmat + (long)n * Kpad + t * BK + gs * 8;
        char* dst = ((char*)w_sw) + q * 1024;    // wave-uniform base; HW adds lane*16
        gload16(src, dst);
    }
}

__device__ __forceinline__ void stage_a_chh(short* a_sw, const float* __restrict__ ag,
                                            int row0, int colofs, int k0, int Kreal, int tid)
{
    const int r = tid >> 2, gq = tid & 3;
    long rg = row0 + r; if (rg >= NNODES) rg = NNODES - 1;
    const float* src = ag + rg * 800 + colofs + k0 + gq * 8;
    short8 v;
    if (k0 + BK <= Kreal) {
        float4 f0 = *(const float4*)(src);
        float4 f1 = *(const float4*)(src + 4);
        v[0] = f2b(f0.x); v[1] = f2b(f0.y); v[2] = f2b(f0.z); v[3] = f2b(f0.w);
        v[4] = f2b(f1.x); v[5] = f2b(f1.y); v[6] = f2b(f1.z); v[7] = f2b(f1.w);
    } else {
        #pragma unroll
        for (int i = 0; i < 8; ++i) {
            int k = k0 + gq * 8 + i;
            float f = (k < Kreal) ? src[i] : 0.0f;
            v[i] = f2b(f);
        }
    }
    int b = r * 64 + gq * 16; b = swz(b);
    *(short8*)((char*)a_sw + b) = v;
}

template<int NF, bool FROM_GLOBAL>
__device__ __forceinline__ void gemm_pass(
    f32x4 (*acc)[8],
    const short (*Ap)[XP],
    const float* __restrict__ ag, int row0, int colofs, int Kreal,
    const short* __restrict__ wmat, int ktiles, int Kpad, int wrows,
    short* a_sw, short* w_sw,
    int tid, int wv, int wm, int wn, int l15, int lg)
{
    for (int t = 0; t < ktiles; ++t) {
        __syncthreads();                                   // previous tile fully consumed
        stage_w(wmat, Kpad, t, wrows, wv, w_sw);
        if constexpr (FROM_GLOBAL)
            stage_a_chh(a_sw, ag, row0, colofs, t * BK, Kreal, tid);
        __syncthreads();                                   // tile ready (drains vmcnt too)
        short8 af[2];
        #pragma unroll
        for (int mi = 0; mi < 2; ++mi) {
            const int row = wm * 32 + mi * 16 + l15;
            if constexpr (FROM_GLOBAL) {
                int b = swz(row * 64 + lg * 16);
                af[mi] = *(const short8*)((const char*)a_sw + b);
            } else {
                af[mi] = *(const short8*)&Ap[row][t * BK + lg * 8];
            }
        }
        #pragma unroll
        for (int ni = 0; ni < NF; ++ni) {
            const int n = (wn * NF + ni) * 16 + l15;
            int b = swz(n * 64 + lg * 16);
            short8 bf = *(const short8*)((const char*)w_sw + b);
            #pragma unroll
            for (int mi = 0; mi < 2; ++mi)
                acc[mi][ni] = __builtin_amdgcn_mfma_f32_16x16x32_bf16(af[mi], bf, acc[mi][ni], 0, 0, 0);
        }
    }
}

#define ZERO_ACC()  { _Pragma("unroll") for (int mi_=0; mi_<2; ++mi_) { _Pragma("unroll") for (int ni_=0; ni_<8; ++ni_) { _Pragma("unroll") for (int q_=0;q_<4;++q_) acc[mi_][ni_][q_] = 0.0f; } } }

__global__ __launch_bounds__(256, 2)
void fused_mfma(const int* __restrict__ tok,
                const float* __restrict__ chc,
                const float* __restrict__ chh,
                const float* __restrict__ emb,
                const float* __restrict__ p1b_, const float* __restrict__ p2b_,
                const float* __restrict__ ixb, const float* __restrict__ ihb,
                const float* __restrict__ fxb, const float* __restrict__ fhb,
                const float* __restrict__ uxb, const float* __restrict__ uhb,
                const float* __restrict__ oxb, const float* __restrict__ ohb,
                const float* __restrict__ fc2b,
                const short* __restrict__ ws,
                float* __restrict__ out)
{
    __shared__ __align__(16) short x_lds[R][XP];   // x, then iu
    __shared__ __align__(16) short hbuf[R][XP];    // ctrl -> hs -> o -> h
    __shared__ __align__(16) short a_sw[R * BK];   // 4KB, swizzled A tile
    __shared__ __align__(16) short w_sw[8192];     // 16KB, swizzled W tile

    const int tid = threadIdx.x;
    const int wv = tid >> 6, wm = wv >> 1, wn = wv & 1;
    const int l15 = tid & 15, lg = (tid & 63) >> 4;
    const int row0 = blockIdx.x * R;

    // ---- init: zero pad cols, gather x=emb[tok] -> x_lds (bf16) ----
    {
        const int r = tid >> 2, q = tid & 3;
        #pragma unroll
        for (int c = 200 + q * 8; c < 200 + q * 8 + 8; ++c) { x_lds[r][c] = 0; hbuf[r][c] = 0; }
        long rg = row0 + r; if (rg >= NNODES) rg = NNODES - 1;
        const float* er = emb + (long)tok[rg] * DDIM;
        const int c0 = q * 50;
        #pragma unroll
        for (int i = 0; i < 50; i += 2) {
            float2 f = *(const float2*)(er + c0 + i);
            x_lds[r][c0 + i]     = f2b(f.x);
            x_lds[r][c0 + i + 1] = f2b(f.y);
        }
    }

    f32x4 acc[2][8];

    // ---- P1: control = relu([ch0|ch1|ch2] @ p1^T + b) -> hbuf ----
    ZERO_ACC();
    gemm_pass<7, true>(acc, nullptr, chh, row0, 0, 600, ws + W_P1, 19, 608, 224,
                       a_sw, w_sw, tid, wv, wm, wn, l15, lg);
    #pragma unroll
    for (int mi = 0; mi < 2; ++mi)
        #pragma unroll
        for (int ni = 0; ni < 7; ++ni) {
            const int col = (wn * 7 + ni) * 16 + l15;
            if (col < DDIM) {
                const float b = p1b_[col];
                #pragma unroll
                for (int j = 0; j < 4; ++j) {
                    const int lrow = wm * 32 + mi * 16 + lg * 4 + j;
                    hbuf[lrow][col] = f2b(fmaxf(acc[mi][ni][j] + b, 0.0f));
                }
            }
        }

    // ---- P2: hs = relu([control|ch3] @ p2^T + b) -> hbuf ----
    ZERO_ACC();
    gemm_pass<7, false>(acc, hbuf, nullptr, 0, 0, 0, ws + W_P2A, 7, 224, 224,
                        a_sw, w_sw, tid, wv, wm, wn, l15, lg);
    gemm_pass<7, true>(acc, nullptr, chh, row0, 600, 200, ws + W_P2B, 7, 224, 224,
                       a_sw, w_sw, tid, wv, wm, wn, l15, lg);
    #pragma unroll
    for (int mi = 0; mi < 2; ++mi)
        #pragma unroll
        for (int ni = 0; ni < 7; ++ni) {
            const int col = (wn * 7 + ni) * 16 + l15;
            if (col < DDIM) {
                const float b = p2b_[col];
                #pragma unroll
                for (int j = 0; j < 4; ++j) {
                    const int lrow = wm * 32 + mi * 16 + lg * 4 + j;
                    hbuf[lrow][col] = f2b(fmaxf(acc[mi][ni][j] + b, 0.0f));
                }
            }
        }

    // ---- I gate ----
    float giu[2][7][4];
    ZERO_ACC();
    gemm_pass<7, false>(acc, x_lds, nullptr, 0, 0, 0, ws + W_IX, 7, 224, 224,
                        a_sw, w_sw, tid, wv, wm, wn, l15, lg);
    gemm_pass<7, false>(acc, hbuf, nullptr, 0, 0, 0, ws + W_IH, 7, 224, 224,
                        a_sw, w_sw, tid, wv, wm, wn, l15, lg);
    #pragma unroll
    for (int mi = 0; mi < 2; ++mi)
        #pragma unroll
        for (int ni = 0; ni < 7; ++ni) {
            const int col = (wn * 7 + ni) * 16 + l15;
            const float b = (col < DDIM) ? (ixb[col] + ihb[col]) : 0.0f;
            #pragma unroll
            for (int j = 0; j < 4; ++j) giu[mi][ni][j] = sgm(acc[mi][ni][j] + b);
        }

    // ---- U gate: giu = i * tanh(u) ----
    ZERO_ACC();
    gemm_pass<7, false>(acc, x_lds, nullptr, 0, 0, 0, ws + W_UX, 7, 224, 224,
                        a_sw, w_sw, tid, wv, wm, wn, l15, lg);
    gemm_pass<7, false>(acc, hbuf, nullptr, 0, 0, 0, ws + W_UH, 7, 224, 224,
                        a_sw, w_sw, tid, wv, wm, wn, l15, lg);
    #pragma unroll
    for (int mi = 0; mi < 2; ++mi)
        #pragma unroll
        for (int ni = 0; ni < 7; ++ni) {
            const int col = (wn * 7 + ni) * 16 + l15;
            const float b = (col < DDIM) ? (uxb[col] + uhb[col]) : 0.0f;
            #pragma unroll
            for (int j = 0; j < 4; ++j) giu[mi][ni][j] *= tanh_fast(acc[mi][ni][j] + b);
        }

    // ---- O gate -> hbuf (hs dead after this pass) ----
    ZERO_ACC();
    gemm_pass<7, false>(acc, x_lds, nullptr, 0, 0, 0, ws + W_OX, 7, 224, 224,
                        a_sw, w_sw, tid, wv, wm, wn, l15, lg);
    gemm_pass<7, false>(acc, hbuf, nullptr, 0, 0, 0, ws + W_OH, 7, 224, 224,
                        a_sw, w_sw, tid, wv, wm, wn, l15, lg);
    __syncthreads();                      // all hs reads done before overwriting hbuf
    #pragma unroll
    for (int mi = 0; mi < 2; ++mi)
        #pragma unroll
        for (int ni = 0; ni < 7; ++ni) {
            const int col = (wn * 7 + ni) * 16 + l15;
            if (col < DDIM) {
                const float b = oxb[col] + ohb[col];
                #pragma unroll
                for (int j = 0; j < 4; ++j) {
                    const int lrow = wm * 32 + mi * 16 + lg * 4 + j;
                    hbuf[lrow][col] = f2b(sgm(acc[mi][ni][j] + b));
                }
            }
        }

    // ---- FX: fxr = x@fx^T + b (kept in regs) ----
    float fxr[2][7][4];
    ZERO_ACC();
    gemm_pass<7, false>(acc, x_lds, nullptr, 0, 0, 0, ws + W_FX, 7, 224, 224,
                        a_sw, w_sw, tid, wv, wm, wn, l15, lg);
    #pragma unroll
    for (int mi = 0; mi < 2; ++mi)
        #pragma unroll
        for (int ni = 0; ni < 7; ++ni) {
            const int col = (wn * 7 + ni) * 16 + l15;
            const float b = (col < DDIM) ? fxb[col] : 0.0f;
            #pragma unroll
            for (int j = 0; j < 4; ++j) fxr[mi][ni][j] = acc[mi][ni][j] + b;
        }

    // ---- store iu -> x_lds (x dead now) ----
    __syncthreads();                      // all x reads (FX) done
    #pragma unroll
    for (int mi = 0; mi < 2; ++mi)
        #pragma unroll
        for (int ni = 0; ni < 7; ++ni) {
            const int col = (wn * 7 + ni) * 16 + l15;
            if (col < DDIM) {
                #pragma unroll
                for (int j = 0; j < 4; ++j) {
                    const int lrow = wm * 32 + mi * 16 + lg * 4 + j;
                    x_lds[lrow][col] = f2b(giu[mi][ni][j]);
                }
            }
        }

    // ---- FH x4: csum = sum_c sigmoid(ch_c@fh^T + fhb + fx) * child_c ----
    float csum[2][7][4];
    #pragma unroll
    for (int mi = 0; mi < 2; ++mi)
        #pragma unroll
        for (int ni = 0; ni < 7; ++ni)
            #pragma unroll
            for (int j = 0; j < 4; ++j) csum[mi][ni][j] = 0.0f;

    for (int c = 0; c < 4; ++c) {
        ZERO_ACC();
        gemm_pass<7, true>(acc, nullptr, chh, row0, c * 200, 200, ws + W_FH, 7, 224, 224,
                           a_sw, w_sw, tid, wv, wm, wn, l15, lg);
        #pragma unroll
        for (int mi = 0; mi < 2; ++mi)
            #pragma unroll
            for (int ni = 0; ni < 7; ++ni) {
                const int col = (wn * 7 + ni) * 16 + l15;
                if (col < DDIM) {
                    const float b = fhb[col];
                    #pragma unroll
                    for (int j = 0; j < 4; ++j) {
                        const int lrow = wm * 32 + mi * 16 + lg * 4 + j;
                        long rg = row0 + lrow; if (rg >= NNODES) rg = NNODES - 1;
                        const float cv = chc[rg * 800 + c * 200 + col];
                        csum[mi][ni][j] += sgm(acc[mi][ni][j] + b + fxr[mi][ni][j]) * cv;
                    }
                }
            }
    }

    // ---- c = iu + csum ; h = o * tanh(c) -> hbuf ----
    #pragma unroll
    for (int mi = 0; mi < 2; ++mi)
        #pragma unroll
        for (int ni = 0; ni < 7; ++ni) {
            const int col = (wn * 7 + ni) * 16 + l15;
            if (col < DDIM) {
                #pragma unroll
                for (int j = 0; j < 4; ++j) {
                    const int lrow = wm * 32 + mi * 16 + lg * 4 + j;
                    const float iu = b2f(x_lds[lrow][col]);
                    const float o  = b2f(hbuf[lrow][col]);
                    const float cc = iu + csum[mi][ni][j];
                    hbuf[lrow][col] = f2b(o * tanh_fast(cc));
                }
            }
        }

    // ---- FC2: logits = h @ fc2^T + b -> out ----
    ZERO_ACC();
    gemm_pass<8, false>(acc, hbuf, nullptr, 0, 0, 0, ws + W_FC2, 7, 224, 256,
                        a_sw, w_sw, tid, wv, wm, wn, l15, lg);
    #pragma unroll
    for (int mi = 0; mi < 2; ++mi)
        #pragma unroll
        for (int ni = 0; ni < 8; ++ni) {
            const int col = (wn * 8 + ni) * 16 + l15;
            if (col < NCLS) {
                const float b = fc2b[col];
                #pragma unroll
                for (int j = 0; j < 4; ++j) {
                    const int lrow = wm * 32 + mi * 16 + lg * 4 + j;
                    const long gr = row0 + lrow;
                    if (gr < NNODES) out[gr * NCLS + col] = acc[mi][ni][j] + b;
                }
            }
        }
}

// ================= fallback fp32 kernel (round-1, used only if ws too small) =================
constexpr int FRT = 32, FBK = 16, FNT = 256, FRTP = FRT + 4, FBUFP = 208;
__device__ __forceinline__ float sgm_f(float x) { return 1.0f / (1.0f + expf(-x)); }

__device__ __forceinline__ void f_stage(
    float (*aT)[FRTP], float (*wt)[FNT], int row0, int k0,
    const float* a1g, int a1pitch, const int* gidx, const float* a1l, int a1lp, int K1,
    const float* a2g, int a2pitch, const float* a2l, int a2lp, int K2,
    const float* wa, int wap, int KW1, const float* wb, int wbp,
    int ncols, int tid)
{
    const int Ktot = K1 + K2;
    {
        const int kk = tid & 15, k = k0 + kk;
        #pragma unroll
        for (int h = 0; h < 2; ++h) {
            const int r = (tid >> 4) + h * 16;
            float v = 0.0f;
            if (k < K1) {
                if (a1l) v = a1l[r * a1lp + k];
                else {
                    const long rb = gidx ? (long)gidx[row0 + r] * a1pitch : (long)(row0 + r) * a1pitch;
                    v = a1g[rb + k];
                }
            } else if (k < Ktot) {
                if (a2l) v = a2l[r * a2lp + (k - K1)];
                else     v = a2g[(long)(row0 + r) * a2pitch + (k - K1)];
            }
            aT[kk][r] = v;
        }
    }
    {
        const int col = tid;
        #pragma unroll
        for (int kk = 0; kk < FBK; ++kk) {
            const int k = k0 + kk; float v = 0.0f;
            if (col < ncols && k < Ktot) {
                if (k < KW1) v = wa[(long)col * wap + k];
                else         v = wb[(long)col * wbp + (k - KW1)];
            }
            wt[kk][col] = v;
        }
    }
}
__device__ __forceinline__ void f_gemm(
    float (*aT)[FRTP], float (*wt)[FNT], float acc[8][4], int row0,
    const float* a1g, int a1p, const int* gidx, const float* a1l, int a1lp, int K1,
    const float* a2g, int a2p, const float* a2l, int a2lp, int K2,
    const float* wa, int wap, int KW1, const float* wb, int wbp,
    int ncols, int tid, int tr, int tc)
{
    #pragma unroll
    for (int j = 0; j < 8; ++j)
        #pragma unroll
        for (int i = 0; i < 4; ++i) acc[j][i] = 0.0f;
    const int Ktot = K1 + K2;
    for (int k0 = 0; k0 < Ktot; k0 += FBK) {
        __syncthreads();
        f_stage(aT, wt, row0, k0, a1g, a1p, gidx, a1l, a1lp, K1, a2g, a2p, a2l, a2lp, K2,
                wa, wap, KW1, wb, wbp, ncols, tid);
        __syncthreads();
        #pragma unroll
        for (int kk = 0; kk < FBK; ++kk) {
            const float w0 = wt[kk][tc*4+0], w1 = wt[kk][tc*4+1], w2 = wt[kk][tc*4+2], w3 = wt[kk][tc*4+3];
            #pragma unroll
            for (int j = 0; j < 8; ++j) {
                const float a = aT[kk][tr*8+j];
                acc[j][0] = fmaf(a, w0, acc[j][0]); acc[j][1] = fmaf(a, w1, acc[j][1]);
                acc[j][2] = fmaf(a, w2, acc[j][2]); acc[j][3] = fmaf(a, w3, acc[j][3]);
            }
        }
    }
}
__global__ __launch_bounds__(256)
void fused_fp32(const int* tok, const float* chc, const float* chh, const float* emb,
                const float* p1w, const float* p1b, const float* p2w, const float* p2b,
                const float* ixw, const float* ixb, const float* ihw, const float* ihb,
                const float* fxw, const float* fxb, const float* fhw, const float* fhb,
                const float* uxw, const float* uxb, const float* uhw, const float* uhb,
                const float* oxw, const float* oxb, const float* ohw, const float* ohb,
                const float* fc2w, const float* fc2b, float* out)
{
    __shared__ float aT[FBK][FRTP]; __shared__ float wt[FBK][FNT]; __shared__ float buf[FRT][FBUFP];
    const int tid = threadIdx.x, tr = tid >> 6, tc = tid & 63, c0 = tc * 4;
    const int row0 = blockIdx.x * FRT;
    float acc[8][4];
    f_gemm(aT, wt, acc, row0, chh, 800, nullptr, nullptr, 0, 600, nullptr,0,nullptr,0,0, p1w,600,600,nullptr,0, DDIM, tid,tr,tc);
    if (c0 < DDIM) { const float4 b = *(const float4*)&p1b[c0];
        #pragma unroll
        for (int j=0;j<8;++j){int r=tr*8+j; buf[r][c0]=fmaxf(acc[j][0]+b.x,0.f); buf[r][c0+1]=fmaxf(acc[j][1]+b.y,0.f); buf[r][c0+2]=fmaxf(acc[j][2]+b.z,0.f); buf[r][c0+3]=fmaxf(acc[j][3]+b.w,0.f);} }
    f_gemm(aT, wt, acc, row0, nullptr,0,nullptr,&buf[0][0],FBUFP,200, chh+600,800,nullptr,0,200, p2w,400,400,nullptr,0, DDIM, tid,tr,tc);
    if (c0 < DDIM) { const float4 b = *(const float4*)&p2b[c0];
        #pragma unroll
        for (int j=0;j<8;++j){int r=tr*8+j; buf[r][c0]=fmaxf(acc[j][0]+b.x,0.f); buf[r][c0+1]=fmaxf(acc[j][1]+b.y,0.f); buf[r][c0+2]=fmaxf(acc[j][2]+b.z,0.f); buf[r][c0+3]=fmaxf(acc[j][3]+b.w,0.f);} }
    f_gemm(aT, wt, acc, row0, emb, DDIM, tok, nullptr,0,200, nullptr,0,nullptr,0,0, fxw,200,200,nullptr,0, DDIM, tid,tr,tc);
    float fxr[8][4];
    { float4 b = make_float4(0,0,0,0); if (c0<DDIM) b = *(const float4*)&fxb[c0];
      #pragma unroll
      for (int j=0;j<8;++j){fxr[j][0]=acc[j][0]+b.x;fxr[j][1]=acc[j][1]+b.y;fxr[j][2]=acc[j][2]+b.z;fxr[j][3]=acc[j][3]+b.w;} }
    float csum[8][4];
    #pragma unroll
    for (int j=0;j<8;++j)
        #pragma unroll
        for (int i=0;i<4;++i) csum[j][i]=0.f;
    for (int cc_=0; cc_<4; ++cc_) {
        f_gemm(aT, wt, acc, row0, chh+cc_*200,800,nullptr,nullptr,0,200, nullptr,0,nullptr,0,0, fhw,200,200,nullptr,0, DDIM, tid,tr,tc);
        if (c0 < DDIM) { const float4 b = *(const float4*)&fhb[c0];
            #pragma unroll
            for (int j=0;j<8;++j){ const long r=row0+tr*8+j; const float4 cv=*(const float4*)&chc[r*800+cc_*200+c0];
                csum[j][0]+=sgm_f(acc[j][0]+b.x+fxr[j][0])*cv.x; csum[j][1]+=sgm_f(acc[j][1]+b.y+fxr[j][1])*cv.y;
                csum[j][2]+=sgm_f(acc[j][2]+b.z+fxr[j][2])*cv.z; csum[j][3]+=sgm_f(acc[j][3]+b.w+fxr[j][3])*cv.w; } }
    }
    f_gemm(aT, wt, acc, row0, emb, DDIM, tok, nullptr,0,200, nullptr,0,&buf[0][0],FBUFP,200, ixw,200,200,ihw,200, DDIM, tid,tr,tc);
    float gi[8][4];
    { float4 b1=make_float4(0,0,0,0),b2=b1; if(c0<DDIM){b1=*(const float4*)&ixb[c0];b2=*(const float4*)&ihb[c0];}
      #pragma unroll
      for(int j=0;j<8;++j){gi[j][0]=sgm_f(acc[j][0]+b1.x+b2.x);gi[j][1]=sgm_f(acc[j][1]+b1.y+b2.y);gi[j][2]=sgm_f(acc[j][2]+b1.z+b2.z);gi[j][3]=sgm_f(acc[j][3]+b1.w+b2.w);} }
    f_gemm(aT, wt, acc, row0, emb, DDIM, tok, nullptr,0,200, nullptr,0,&buf[0][0],FBUFP,200, uxw,200,200,uhw,200, DDIM, tid,tr,tc);
    float cval[8][4];
    { float4 b1=make_float4(0,0,0,0),b2=b1; if(c0<DDIM){b1=*(const float4*)&uxb[c0];b2=*(const float4*)&uhb[c0];}
      #pragma unroll
      for(int j=0;j<8;++j){cval[j][0]=gi[j][0]*tanhf(acc[j][0]+b1.x+b2.x)+csum[j][0];cval[j][1]=gi[j][1]*tanhf(acc[j][1]+b1.y+b2.y)+csum[j][1];
                           cval[j][2]=gi[j][2]*tanhf(acc[j][2]+b1.z+b2.z)+csum[j][2];cval[j][3]=gi[j][3]*tanhf(acc[j][3]+b1.w+b2.w)+csum[j][3];} }
    f_gemm(aT, wt, acc, row0, emb, DDIM, tok, nullptr,0,200, nullptr,0,&buf[0][0],FBUFP,200, oxw,200,200,ohw,200, DDIM, tid,tr,tc);
    if (c0 < DDIM) { const float4 b1=*(const float4*)&oxb[c0], b2=*(const float4*)&ohb[c0];
        #pragma unroll
        for(int j=0;j<8;++j){int r=tr*8+j;
            buf[r][c0]=sgm_f(acc[j][0]+b1.x+b2.x)*tanhf(cval[j][0]); buf[r][c0+1]=sgm_f(acc[j][1]+b1.y+b2.y)*tanhf(cval[j][1]);
            buf[r][c0+2]=sgm_f(acc[j][2]+b1.z+b2.z)*tanhf(cval[j][2]); buf[r][c0+3]=sgm_f(acc[j][3]+b1.w+b2.w)*tanhf(cval[j][3]);} }
    f_gemm(aT, wt, acc, row0, nullptr,0,nullptr,&buf[0][0],FBUFP,200, nullptr,0,nullptr,0,0, fc2w,200,200,nullptr,0, NCLS, tid,tr,tc);
    #pragma unroll
    for (int j=0;j<8;++j){ const long r=row0+tr*8+j;
        #pragma unroll
        for (int i=0;i<4;++i){ const int col=c0+i; if (col<NCLS) out[r*NCLS+col]=acc[j][i]+fc2b[col]; } }
}

// ================= launch =================
extern "C" void kernel_launch(void* const* d_in, const int* in_sizes, int n_in,
                              void* d_out, int out_size, void* d_ws, size_t ws_size,
                              hipStream_t stream)
{
    const int*   tok  = (const int*)  d_in[0];
    const float* chc  = (const float*)d_in[1];
    const float* chh  = (const float*)d_in[2];
    const float* emb  = (const float*)d_in[3];
    const float* p1w  = (const float*)d_in[4];
    const float* p1b  = (const float*)d_in[5];
    const float* p2w  = (const float*)d_in[6];
    const float* p2b  = (const float*)d_in[7];
    const float* ixw  = (const float*)d_in[8];
    const float* ixb  = (const float*)d_in[9];
    const float* ihw  = (const float*)d_in[10];
    const float* ihb  = (const float*)d_in[11];
    const float* fxw  = (const float*)d_in[12];
    const float* fxb  = (const float*)d_in[13];
    const float* fhw  = (const float*)d_in[14];
    const float* fhb  = (const float*)d_in[15];
    const float* uxw  = (const float*)d_in[16];
    const float* uxb  = (const float*)d_in[17];
    const float* uhw  = (const float*)d_in[18];
    const float* uhb  = (const float*)d_in[19];
    const float* oxw  = (const float*)d_in[20];
    const float* oxb  = (const float*)d_in[21];
    const float* ohw  = (const float*)d_in[22];
    const float* ohb  = (const float*)d_in[23];
    const float* fc2w = (const float*)d_in[24];
    const float* fc2b = (const float*)d_in[25];
    float* out = (float*)d_out;

    if (ws_size >= W_TOTAL_BYTES) {
        short* ws = (short*)d_ws;
        hipLaunchKernelGGL(wprep, dim3((W_TOTAL_ELEMS + 255) / 256), dim3(256), 0, stream,
                           p1w, p2w, fxw, fhw, ixw, ihw, uxw, uhw, oxw, ohw, fc2w, ws);
        hipLaunchKernelGGL(fused_mfma, dim3((NNODES + R - 1) / R), dim3(256), 0, stream,
                           tok, chc, chh, emb,
                           p1b, p2b, ixb, ihb, fxb, fhb, uxb, uhb, oxb, ohb, fc2b,
                           ws, out);
    } else {
        hipLaunchKernelGGL(fused_fp32, dim3(NNODES / FRT), dim3(256), 0, stream,
                           tok, chc, chh, emb, p1w, p1b, p2w, p2b,
                           ixw, ixb, ihw, ihb, fxw, fxb, fhw, fhb,
                           uxw, uxb, uhw, uhb, oxw, oxb, ohw, ohb, fc2w, fc2b, out);
    }
}